// Round 8
// baseline (1101.870 us; speedup 1.0000x reference)
//
#include <hip/hip_runtime.h>

// Problem: bs=8, seq=16, hw=32*32=1024, ck=256, cv=3, steps=seq-1=15
// R13 = R7's verified factored design with the R10-proven spill fix.
// Coop launch abandoned (2x container failures). Structure:
//  - scan_state (R10 variant, verified 79us): kh/m_kh fp16 for all steps.
//  - p_all: ALL attention matrices (both softmax(k k^T) and softmax(k m_k^T))
//    computed fully parallel across steps; P~ fp16 + per-wave-chunk softmax
//    corrections C. FIX vs R7: __launch_bounds__(512,1) -> VGPR cap 256
//    (demand ~180; R7's cap 128 spilled ~50 regs in the MFMA loop -> 378us
//    at MfmaUtil 7%).
//  - absorb (verified, 18us/step): the only serial kernel; tiny MFMA combine
//    rec = 0.9 S pv + 0.1 T mv with fp32-exact hi/lo-split V, fused m_v EMA.
#define BS 8
#define SEQ 16
#define HW 1024
#define CK 256
#define CV 3
#define STEPS 15

#define SKP 264   // padded fp16 LDS row stride (256+8)
#define VTP 1032  // padded fp16 Vt row stride (1024+8)

typedef unsigned short u16;
typedef _Float16 half8 __attribute__((ext_vector_type(8)));  // MFMA A/B frag
typedef float floatx4 __attribute__((ext_vector_type(4)));   // MFMA C/D frag

__device__ __forceinline__ u16 f2h(float f) {
  _Float16 h = (_Float16)f;
  return __builtin_bit_cast(unsigned short, h);
}
__device__ __forceinline__ float h2f(u16 u) {
  _Float16 h = __builtin_bit_cast(_Float16, u);
  return (float)h;
}

// ---- scan_state (once, fully parallel): kh_all = fp16(k[:, i]) for all i,
//      m_kh_all[i] = m_k EMA (fp16 state, fp32 math), pv0 = v[:,0], m_v0 = 0,
//      gt = v[:,1:].  4-elem chunks: 524288 chains, next-step k prefetched. ----
__global__ __launch_bounds__(256) void scan_state(
    const float* __restrict__ k, const float* __restrict__ v,
    const float* __restrict__ att,
    u16* __restrict__ kh_all, u16* __restrict__ m_kh_all,
    float* __restrict__ pv0, float* __restrict__ mv0,
    float* __restrict__ out)
{
  long idx = (long)blockIdx.x * 256 + threadIdx.x;
  long stride = (long)gridDim.x * 256;
  const long NCH = (long)BS * HW * 64;         // 524,288 4-elem chunks
  const long SSTR = (long)HW * CK;             // per-step element stride
  for (long t = idx; t < NCH; t += stride) {
    long b = t >> 16;                          // / (HW*64)
    long r = t & 65535;
    long p = r >> 6, s = r & 63;
    const float* kp = k + ((long)b * SEQ * HW + p) * CK + s * 4;
    u16* khp = kh_all + ((long)b * SEQ * HW + p) * CK + s * 4;
    u16* mkp = m_kh_all + ((long)b * STEPS * HW + p) * CK + s * 4;
    const float* ap = att + (long)b * SEQ * HW + p;
    u16 mh[4] = {0, 0, 0, 0};
    float4 nxt = *(const float4*)kp;
    for (int i = 0; i < SEQ; ++i) {
      float4 cur = nxt;
      if (i + 1 < SEQ) nxt = *(const float4*)(kp + (long)(i + 1) * SSTR);
      float kf[4] = {cur.x, cur.y, cur.z, cur.w};
      u16 h4[4];
      #pragma unroll
      for (int j = 0; j < 4; ++j) h4[j] = f2h(kf[j]);
      *(int2*)(khp + (long)i * SSTR) = *(const int2*)h4;
      if (i < STEPS) {
        float a = ap[(long)i * HW];
        float g = 1.0f / (1.0f + __expf(-a)), og = 1.0f - g;
        #pragma unroll
        for (int j = 0; j < 4; ++j)
          mh[j] = f2h(fmaf(g, kf[j], og * h2f(mh[j])));
        *(int2*)(mkp + (long)i * SSTR) = *(const int2*)mh;
      }
    }
  }
  // pv0 = v[:,0], m_v0 = 0
  const long NV = (long)BS * HW * CV;
  for (long t = idx; t < NV; t += stride) {
    long b = t / (HW * CV), r = t - b * (HW * CV);
    pv0[t] = v[(long)b * SEQ * HW * CV + r];
    mv0[t] = 0.0f;
  }
  // gt = v[:,1:]
  const long NG = (long)BS * STEPS * HW * CV;
  for (long t = idx; t < NG; t += stride) {
    long b = t / (STEPS * HW * CV), r = t - b * (STEPS * HW * CV);
    long i = r / (HW * CV), rr = r - i * (HW * CV);
    out[NG + t] = v[((long)b * SEQ + i + 1) * (HW * CV) + rr];
  }
}

// --------- p_all: ALL attention matrices for a pass, fully parallel ---------
// grid ps*256 blocks, 512 thr = 8 waves. id%8 -> b = XCD-local batch.
// Per wave w (p-range [w*128,(w+1)*128)): scores held in regs (64/lane/mat),
// wave-level max/sum, store P~ = exp(s - M_w) fp16 to global, publish (M_w,l_w)
// to LDS; block-level merge writes C[q][w] = exp(M_w - M)/L.
// __launch_bounds__(512,1): VGPR cap 256 -> no spills (demand ~180).
__global__ __launch_bounds__(512, 1) void p_all(
    const u16* __restrict__ kh_all, const u16* __restrict__ m_kh_all,
    u16* __restrict__ P, float* __restrict__ C, int s0)
{
  __shared__ u16 Kq[32 * SKP];          // q-tile fp16 (16.9 KB)
  __shared__ float Mg[8][2][32][2];     // per-wave (M, l) per q (4 KB)

  const int id = blockIdx.x;
  const int b = id & 7;                 // batch == XCD (round-robin %8)
  const int j = (id >> 3) & 31;         // q-tile
  const int ls = id >> 8;               // pass-local step
  const int step = s0 + ls;
  const int g = ls * 8 + b;             // group index into P/C
  const int q0 = j * 32;
  const int tid = threadIdx.x;
  const int w = tid >> 6, lane = tid & 63;
  const int r = lane & 15, rg = lane >> 4;

  const u16* Kn = kh_all + (long)(b * SEQ + step + 1) * HW * CK;  // q side
  const u16* Kc = kh_all + (long)(b * SEQ + step) * HW * CK;      // p side
  const u16* Mb = m_kh_all + (long)(b * STEPS + step) * HW * CK;  // p side

  { // stage q-tile: 1024 16B-chunks over 512 threads
    #pragma unroll
    for (int jj = 0; jj < 2; ++jj) {
      int c = tid + jj * 512;
      int row = c >> 5, off = (c & 31) * 8;
      *(int4*)&Kq[row * SKP + off] = *(const int4*)(Kn + (long)(q0 + row) * CK + off);
    }
  }
  __syncthreads();

  half8 Bq[2][8];
  #pragma unroll
  for (int qi = 0; qi < 2; ++qi)
    #pragma unroll
    for (int kk = 0; kk < 8; ++kk)
      Bq[qi][kk] = *(const half8*)&Kq[(qi * 16 + r) * SKP + kk * 32 + rg * 8];

  #pragma unroll
  for (int mat = 0; mat < 2; ++mat) {
    const u16* Ab = mat ? Mb : Kc;
    floatx4 S[2][8];
    #pragma unroll
    for (int pc = 0; pc < 4; ++pc)
      #pragma unroll
      for (int pi = 0; pi < 2; ++pi) {
        const int pr = w * 128 + pc * 32 + pi * 16;
        half8 A[8];
        #pragma unroll
        for (int kk = 0; kk < 8; ++kk)
          A[kk] = *(const half8*)(Ab + (long)(pr + r) * CK + kk * 32 + rg * 8);
        floatx4 c0 = {0.f, 0.f, 0.f, 0.f}, c1 = {0.f, 0.f, 0.f, 0.f};
        #pragma unroll
        for (int kk = 0; kk < 8; ++kk) {
          c0 = __builtin_amdgcn_mfma_f32_16x16x32_f16(A[kk], Bq[0][kk], c0, 0, 0, 0);
          c1 = __builtin_amdgcn_mfma_f32_16x16x32_f16(A[kk], Bq[1][kk], c1, 0, 0, 0);
        }
        S[0][pc * 2 + pi] = c0;
        S[1][pc * 2 + pi] = c1;
      }
    #pragma unroll
    for (int qi = 0; qi < 2; ++qi) {
      float m = -1e30f;
      #pragma unroll
      for (int idx = 0; idx < 8; ++idx)
        #pragma unroll
        for (int jj = 0; jj < 4; ++jj)
          m = fmaxf(m, S[qi][idx][jj]);
      m = fmaxf(m, __shfl_xor(m, 16));
      m = fmaxf(m, __shfl_xor(m, 32));
      float l = 0.f;
      #pragma unroll
      for (int idx = 0; idx < 8; ++idx)
        #pragma unroll
        for (int jj = 0; jj < 4; ++jj) {
          float e = __expf(S[qi][idx][jj] - m);
          S[qi][idx][jj] = e;
          l += e;
        }
      l += __shfl_xor(l, 16);
      l += __shfl_xor(l, 32);
      if (rg == 0) { Mg[w][mat][qi * 16 + r][0] = m; Mg[w][mat][qi * 16 + r][1] = l; }
      // store P~ rows (fp16, [q][p] row-major)
      u16* Pr = P + ((long)(g * 2 + mat) * HW + q0 + qi * 16 + r) * HW;
      #pragma unroll
      for (int idx = 0; idx < 8; ++idx) {
        int pc = idx >> 1, pi = idx & 1;
        int p = w * 128 + pc * 32 + pi * 16 + rg * 4;
        u16 t4[4] = {f2h(S[qi][idx][0]), f2h(S[qi][idx][1]),
                     f2h(S[qi][idx][2]), f2h(S[qi][idx][3])};
        *(int2*)&Pr[p] = *(const int2*)t4;
      }
    }
  }
  __syncthreads();
  if (tid < 64) {  // block-level softmax merge -> corrections C[q][w]
    int mat = tid >> 5, q = tid & 31;
    float M = -1e30f;
    #pragma unroll
    for (int w8 = 0; w8 < 8; ++w8) M = fmaxf(M, Mg[w8][mat][q][0]);
    float L = 0.f;
    #pragma unroll
    for (int w8 = 0; w8 < 8; ++w8)
      L += Mg[w8][mat][q][1] * __expf(Mg[w8][mat][q][0] - M);
    float iL = 1.0f / L;
    float* Cg = C + ((long)g * 2 + mat) * HW * 8 + (long)(q0 + q) * 8;
    #pragma unroll
    for (int w8 = 0; w8 < 8; ++w8)
      Cg[w8] = __expf(Mg[w8][mat][q][0] - M) * iL;
  }
}

// --------- absorb (the only serial kernel, 15x): rec = 0.9 S pv + 0.1 T mv ---
// grid (8, 32), 256 thr = 4 waves = (mat, qsub). MFMA: A = V^T in LDS as
// hi/lo fp16 split (fp32-exact), B = P~ rows streamed from global.
// D[c][q]: col=lane&15 -> q, rows=(lane>>4)*4+reg -> c (real c=0..2 in rg=0).
// Fused m_v EMA (published by blockIdx.y==0); per-128p-chunk correction C.
__global__ __launch_bounds__(256) void absorb(
    const u16* __restrict__ P, const float* __restrict__ C,
    const float* __restrict__ v, const int* __restrict__ seq_mask,
    const float* __restrict__ att,
    const float* __restrict__ mv_in, float* __restrict__ mv_out,
    const float* __restrict__ pv_in, float* __restrict__ pv_out,
    float* __restrict__ out, int step, int g0)
{
  __shared__ __align__(16) u16 Vt[2][2][4][VTP];  // [mat][hi/lo][c-row(4)][p] 33 KB
  __shared__ float Cs[2][32][8];                  // corrections (2 KB)
  __shared__ float Acc[2][2][16][3];              // per-wave results (768 B)

  const int b = blockIdx.x, q0 = blockIdx.y * 32;
  const int tid = threadIdx.x;
  const int g = g0 + b;

  { // stage corrections
    const float* Cg = C + (long)g * 2 * HW * 8;
    for (int t2 = tid; t2 < 512; t2 += 256) {
      int mat = t2 >> 8, rest = t2 & 255, q = rest >> 3, w8 = rest & 7;
      Cs[mat][q][w8] = Cg[(long)mat * HW * 8 + (long)(q0 + q) * 8 + w8];
    }
  }
  { // stage V^T (hi/lo split) + fused m_v EMA + publish
    const float* ar = att + (long)(b * SEQ + step) * HW;
    #pragma unroll
    for (int pp = 0; pp < 4; ++pp) {
      int p = tid * 4 + pp;
      float a = ar[p];
      float gg = 1.0f / (1.0f + __expf(-a));
      float og = 1.0f - gg;
      long base = ((long)b * HW + p) * CV;
      #pragma unroll
      for (int c = 0; c < CV; ++c) {
        float pv = pv_in[base + c];
        float mv = fmaf(gg, pv, og * mv_in[base + c]);
        if (blockIdx.y == 0) mv_out[base + c] = mv;
        u16 sh = f2h(pv); u16 sl = f2h(pv - h2f(sh));
        u16 mh = f2h(mv); u16 ml = f2h(mv - h2f(mh));
        Vt[0][0][c][p] = sh; Vt[0][1][c][p] = sl;
        Vt[1][0][c][p] = mh; Vt[1][1][c][p] = ml;
      }
      // zero the clamp row (r>=3 lanes read row 3)
      Vt[0][0][3][p] = 0; Vt[0][1][3][p] = 0;
      Vt[1][0][3][p] = 0; Vt[1][1][3][p] = 0;
    }
  }
  __syncthreads();

  const int w4 = tid >> 6, lane = tid & 63, r = lane & 15, rg = lane >> 4;
  const int qsub = w4 & 1, mat = w4 >> 1;
  const int rc = r < 3 ? r : 3;
  const u16* Pr = P + ((long)(g * 2 + mat) * HW + q0 + qsub * 16 + r) * HW;

  floatx4 acc = {0.f, 0.f, 0.f, 0.f};
  #pragma unroll
  for (int wg = 0; wg < 8; ++wg) {
    floatx4 D = {0.f, 0.f, 0.f, 0.f};
    #pragma unroll
    for (int ch = 0; ch < 4; ++ch) {
      int p0 = wg * 128 + ch * 32 + rg * 8;
      half8 Bf  = *(const half8*)(Pr + p0);
      half8 Ahi = *(const half8*)&Vt[mat][0][rc][p0];
      half8 Alo = *(const half8*)&Vt[mat][1][rc][p0];
      D = __builtin_amdgcn_mfma_f32_16x16x32_f16(Ahi, Bf, D, 0, 0, 0);
      D = __builtin_amdgcn_mfma_f32_16x16x32_f16(Alo, Bf, D, 0, 0, 0);
    }
    float Cv = Cs[mat][qsub * 16 + r][wg];
    acc[0] = fmaf(Cv, D[0], acc[0]);
    acc[1] = fmaf(Cv, D[1], acc[1]);
    acc[2] = fmaf(Cv, D[2], acc[2]);
    acc[3] = fmaf(Cv, D[3], acc[3]);
  }
  if (rg == 0) {  // rows 0..2 = c, col = r = q-sub-index
    Acc[mat][qsub][r][0] = acc[0];
    Acc[mat][qsub][r][1] = acc[1];
    Acc[mat][qsub][r][2] = acc[2];
  }
  __syncthreads();

  if (tid < 128) {
    int q = tid >> 2, c = tid & 3;
    if (c < CV) {
      float rec = 0.9f * Acc[0][q >> 4][q & 15][c] + 0.1f * Acc[1][q >> 4][q & 15][c];
      const int maskv = seq_mask[b * SEQ + step];
      const int qg = q0 + q;
      out[((long)(b * STEPS + step) * HW + qg) * CV + c] = rec;
      const float vr = v[((long)(b * SEQ + step) * HW + qg) * CV + c];
      pv_out[((long)(b * HW + qg)) * CV + c] = maskv ? vr : rec;
    }
  }
}

extern "C" void kernel_launch(void* const* d_in, const int* in_sizes, int n_in,
                              void* d_out, int out_size, void* d_ws, size_t ws_size,
                              hipStream_t stream) {
  const float* k   = (const float*)d_in[0];
  const float* v   = (const float*)d_in[1];
  const float* att = (const float*)d_in[2];
  const int* seq_mask = (const int*)d_in[3];
  float* out = (float*)d_out;
  char* ws = (char*)d_ws;

  const size_t KH_ALL  = (size_t)BS * SEQ * HW * CK * 2;    //  67,108,864
  const size_t MKH_ALL = (size_t)BS * STEPS * HW * CK * 2;  //  62,914,560
  const size_t SV      = (size_t)BS * HW * CV * 4;          //      98,304
  const size_t PSTEP_P = (size_t)BS * 2 * HW * HW * 2;      //  33,554,432
  const size_t PSTEP_C = (size_t)BS * 2 * HW * 8 * 4;       //     524,288
  const size_t FIXED   = KH_ALL + MKH_ALL + 4 * SV;         // 130,416,640

  int ps_max = (ws_size > FIXED) ? (int)((ws_size - FIXED) / (PSTEP_P + PSTEP_C)) : 1;
  if (ps_max < 1) ps_max = 1;
  if (ps_max > STEPS) ps_max = STEPS;
  const int PASS = ps_max < 8 ? ps_max : 8;

  u16*   kh_all   = (u16*)(ws);
  u16*   m_kh_all = (u16*)(ws + KH_ALL);
  float* pvA      = (float*)(ws + KH_ALL + MKH_ALL);
  float* pvB      = (float*)(ws + KH_ALL + MKH_ALL + SV);
  float* mvA      = (float*)(ws + KH_ALL + MKH_ALL + 2 * SV);
  float* mvB      = (float*)(ws + KH_ALL + MKH_ALL + 3 * SV);
  float* Cbuf     = (float*)(ws + FIXED);
  u16*   Pbuf     = (u16*)(ws + FIXED + (size_t)PASS * PSTEP_C);

  // all conversions + m_k EMA scan + pv0/mv0 init + gt copy (parallel)
  scan_state<<<2048, 256, 0, stream>>>(k, v, att, kh_all, m_kh_all, pvA, mvA, out);

  for (int s0 = 0; s0 < STEPS; s0 += PASS) {
    int ps = (s0 + PASS <= STEPS) ? PASS : (STEPS - s0);
    // all GEMM+softmax work for this pass, fully parallel across steps
    p_all<<<ps * 256, 512, 0, stream>>>(kh_all, m_kh_all, Pbuf, Cbuf, s0);
    // serial linear combine
    for (int i = s0; i < s0 + ps; ++i) {
      int ls = i - s0;
      float* pin  = (i & 1) ? pvB : pvA;
      float* pout = (i & 1) ? pvA : pvB;
      float* mvi  = (i & 1) ? mvB : mvA;
      float* mvo  = (i & 1) ? mvA : mvB;
      absorb<<<dim3(BS, 32), 256, 0, stream>>>(Pbuf, Cbuf, v, seq_mask, att,
                                               mvi, mvo, pin, pout, out, i, ls * 8);
    }
  }
}

// Round 9
// 1014.928 us; speedup vs baseline: 1.0857x; 1.0857x over previous
//
#include <hip/hip_runtime.h>

// Problem: bs=8, seq=16, hw=32*32=1024, ck=256, cv=3, steps=seq-1=15
// R14 design: R10 (verified 720us) with the 15-launch serial chain replaced
// by ONE normal launch + software grid barrier between steps.
//  - R13 post-mortem: VGPR_Count=128 + ~128 AGPR (unified file) = 256/wave ->
//    1 block/CU (Occupancy 21.5%): p_all was latency-bound, NOT spilling;
//    launch_bounds caps were never the lever. Coop-launch deaths explained:
//    regs >256/wave make an 8-wave block unschedulable -> hang.
//  - grid (8,32) = 256 blocks = exactly 1/CU -> all blocks resident by
//    construction -> software barrier is safe WITHOUT the coop API:
//    per-step device-scope atomic counter (zeroed by scan_state, stream-
//    ordered) + acquire-load spin + s_sleep.
//  - attn body = bit-exact R10 attn_step (verified 42.7us/step, <=256 regs).
#define BS 8
#define SEQ 16
#define HW 1024
#define CK 256
#define CV 3
#define STEPS 15

#define SKP 264   // padded fp16 LDS row stride (256+8)
#define NBLK (BS * 32)   // 256 blocks in the attn grid

typedef unsigned short u16;
typedef _Float16 half8 __attribute__((ext_vector_type(8)));  // MFMA A/B frag
typedef float floatx4 __attribute__((ext_vector_type(4)));   // MFMA C/D frag

__device__ __forceinline__ u16 f2h(float f) {
  _Float16 h = (_Float16)f;
  return __builtin_bit_cast(unsigned short, h);
}
__device__ __forceinline__ float h2f(u16 u) {
  _Float16 h = __builtin_bit_cast(_Float16, u);
  return (float)h;
}

// ---- scan_state (once, fully parallel): kh_all = fp16(k[:, i]) for all i,
//      m_kh_all[i] = m_k EMA (fp16 state, fp32 math), pv0 = v[:,0], m_v0 = 0,
//      gt = v[:,1:], barrier counters zeroed.  4-elem chunks, prefetched. ----
__global__ __launch_bounds__(256) void scan_state(
    const float* __restrict__ k, const float* __restrict__ v,
    const float* __restrict__ att,
    u16* __restrict__ kh_all, u16* __restrict__ m_kh_all,
    float* __restrict__ pv0, float* __restrict__ mv0,
    float* __restrict__ out, int* __restrict__ bar)
{
  long idx = (long)blockIdx.x * 256 + threadIdx.x;
  long stride = (long)gridDim.x * 256;
  if (idx < STEPS) bar[idx * 16] = 0;          // zero barrier counters (64B apart)
  const long NCH = (long)BS * HW * 64;         // 524,288 4-elem chunks
  const long SSTR = (long)HW * CK;             // per-step element stride
  for (long t = idx; t < NCH; t += stride) {
    long b = t >> 16;                          // / (HW*64)
    long r = t & 65535;
    long p = r >> 6, s = r & 63;
    const float* kp = k + ((long)b * SEQ * HW + p) * CK + s * 4;
    u16* khp = kh_all + ((long)b * SEQ * HW + p) * CK + s * 4;
    u16* mkp = m_kh_all + ((long)b * STEPS * HW + p) * CK + s * 4;
    const float* ap = att + (long)b * SEQ * HW + p;
    u16 mh[4] = {0, 0, 0, 0};
    float4 nxt = *(const float4*)kp;
    for (int i = 0; i < SEQ; ++i) {
      float4 cur = nxt;
      if (i + 1 < SEQ) nxt = *(const float4*)(kp + (long)(i + 1) * SSTR);
      float kf[4] = {cur.x, cur.y, cur.z, cur.w};
      u16 h4[4];
      #pragma unroll
      for (int j = 0; j < 4; ++j) h4[j] = f2h(kf[j]);
      *(int2*)(khp + (long)i * SSTR) = *(const int2*)h4;
      if (i < STEPS) {
        float a = ap[(long)i * HW];
        float g = 1.0f / (1.0f + __expf(-a)), og = 1.0f - g;
        #pragma unroll
        for (int j = 0; j < 4; ++j)
          mh[j] = f2h(fmaf(g, kf[j], og * h2f(mh[j])));
        *(int2*)(mkp + (long)i * SSTR) = *(const int2*)mh;
      }
    }
  }
  // pv0 = v[:,0], m_v0 = 0
  const long NV = (long)BS * HW * CV;
  for (long t = idx; t < NV; t += stride) {
    long b = t / (HW * CV), r = t - b * (HW * CV);
    pv0[t] = v[(long)b * SEQ * HW * CV + r];
    mv0[t] = 0.0f;
  }
  // gt = v[:,1:]
  const long NG = (long)BS * STEPS * HW * CV;
  for (long t = idx; t < NG; t += stride) {
    long b = t / (STEPS * HW * CV), r = t - b * (STEPS * HW * CV);
    long i = r / (HW * CV), rr = r - i * (HW * CV);
    out[NG + t] = v[((long)b * SEQ + i + 1) * (HW * CV) + rr];
  }
}

// --------- attn_span: all steps in one NORMAL launch; software grid barrier ---
// grid (BS, 32): block = (batch, 32 q-rows), 512 thr = 8 waves, 1 block/CU
// (LDS 51.7KB, 256 blocks = 256 CUs -> all resident). Bit-exact R10 body.
__global__ __launch_bounds__(512, 1) void attn_span(
    const u16* __restrict__ kh_all, const u16* __restrict__ m_kh_all,
    const float* __restrict__ v, const int* __restrict__ seq_mask,
    const float* __restrict__ att,
    float* __restrict__ mvA, float* __restrict__ mvB,
    float* __restrict__ pvA, float* __restrict__ pvB,
    float* __restrict__ out, int* __restrict__ bar)
{
  __shared__ u16 Kq[32 * SKP];          // q-tile fp16 (16.9 KB)
  __shared__ float Vp[HW * CV];         // prev_v staged (12 KB)
  __shared__ float Vm[HW * CV];         // m_v (updated) staged (12 KB)
  __shared__ float Mg[8][2][32][5];     // per-wave partial states (10.2 KB)

  const int b = blockIdx.x;
  const int q0 = blockIdx.y * 32;
  const int tid = threadIdx.x;
  const int w = tid >> 6, lane = tid & 63;
  const int r = lane & 15, rg = lane >> 4;

  for (int step = 0; step < STEPS; ++step) {
    const float* pv_in  = (step & 1) ? pvB : pvA;
    float*       pv_out = (step & 1) ? pvA : pvB;
    const float* mv_in  = (step & 1) ? mvB : mvA;
    float*       mv_out = (step & 1) ? mvA : mvB;

    const u16* Kn = kh_all + (long)(b * SEQ + step + 1) * HW * CK;  // q side
    const u16* Kc = kh_all + (long)(b * SEQ + step) * HW * CK;      // p side
    const u16* Mb = m_kh_all + (long)(b * STEPS + step) * HW * CK;  // p side

    { // stage q-tile: 1024 16B-chunks over 512 threads
      #pragma unroll
      for (int j = 0; j < 2; ++j) {
        int c = tid + j * 512;
        int row = c >> 5, off = (c & 31) * 8;
        *(int4*)&Kq[row * SKP + off] = *(const int4*)(Kn + (long)(q0 + row) * CK + off);
      }
    }
    { // stage V values + fused m_v EMA: m_v_i = g*pv_i + (1-g)*m_v_{i-1}
      const float* ar = att + (long)(b * SEQ + step) * HW;
      #pragma unroll
      for (int j = 0; j < 2; ++j) {
        int row = tid + j * 512;
        float a = ar[row];
        float g = 1.0f / (1.0f + __expf(-a));
        float og = 1.0f - g;
        long base = (long)(b * HW + row) * CV;
        #pragma unroll
        for (int c = 0; c < CV; ++c) {
          float pv = pv_in[base + c];
          float mv = fmaf(g, pv, og * mv_in[base + c]);
          Vp[row * CV + c] = pv;
          Vm[row * CV + c] = mv;
          if (blockIdx.y == 0) mv_out[base + c] = mv;
        }
      }
    }
    __syncthreads();

    // B fragments (q-tile) held in registers: 2 q-subtiles x 8 k-steps
    half8 Bq[2][8];
    #pragma unroll
    for (int qi = 0; qi < 2; ++qi)
      #pragma unroll
      for (int kk = 0; kk < 8; ++kk)
        Bq[qi][kk] = *(const half8*)&Kq[(qi * 16 + r) * SKP + kk * 32 + rg * 8];

    // online state per (mat, qi)
    float mx[2][2], l[2][2], acc[2][2][3];
    #pragma unroll
    for (int m = 0; m < 2; ++m)
      #pragma unroll
      for (int qi = 0; qi < 2; ++qi) {
        mx[m][qi] = -1e30f; l[m][qi] = 0.f;
        acc[m][qi][0] = acc[m][qi][1] = acc[m][qi][2] = 0.f;
      }

    #pragma unroll
    for (int pc = 0; pc < 4; ++pc) {
      const int p0 = w * 128 + pc * 32;
      #pragma unroll
      for (int mat = 0; mat < 2; ++mat) {
        const u16* Ab = mat ? Mb : Kc;
        const float* Vb = mat ? Vm : Vp;
        #pragma unroll
        for (int pi = 0; pi < 2; ++pi) {
          const int pr = p0 + pi * 16;
          // V values for this lane's 4 p-rows, from LDS
          float Vv[4][3];
          #pragma unroll
          for (int j = 0; j < 4; ++j) {
            const float* vp = Vb + (pr + rg * 4 + j) * CV;
            Vv[j][0] = vp[0]; Vv[j][1] = vp[1]; Vv[j][2] = vp[2];
          }
          // A fragments: 16 p-rows x 32-k per kk step
          half8 A[8];
          #pragma unroll
          for (int kk = 0; kk < 8; ++kk)
            A[kk] = *(const half8*)(Ab + (long)(pr + r) * CK + kk * 32 + rg * 8);
          floatx4 c0 = {0.f, 0.f, 0.f, 0.f}, c1 = {0.f, 0.f, 0.f, 0.f};
          #pragma unroll
          for (int kk = 0; kk < 8; ++kk) {
            c0 = __builtin_amdgcn_mfma_f32_16x16x32_f16(A[kk], Bq[0][kk], c0, 0, 0, 0);
            c1 = __builtin_amdgcn_mfma_f32_16x16x32_f16(A[kk], Bq[1][kk], c1, 0, 0, 0);
          }
          // absorb 4 p-values per qi into online state
          #pragma unroll
          for (int qi = 0; qi < 2; ++qi) {
            floatx4 cc = qi ? c1 : c0;
            float tmax = fmaxf(fmaxf(cc[0], cc[1]), fmaxf(cc[2], cc[3]));
            tmax = fmaxf(tmax, mx[mat][qi]);
            float sc = __expf(mx[mat][qi] - tmax);
            l[mat][qi] *= sc;
            acc[mat][qi][0] *= sc; acc[mat][qi][1] *= sc; acc[mat][qi][2] *= sc;
            #pragma unroll
            for (int j = 0; j < 4; ++j) {
              float e = __expf(cc[j] - tmax);
              l[mat][qi] += e;
              acc[mat][qi][0] = fmaf(e, Vv[j][0], acc[mat][qi][0]);
              acc[mat][qi][1] = fmaf(e, Vv[j][1], acc[mat][qi][1]);
              acc[mat][qi][2] = fmaf(e, Vv[j][2], acc[mat][qi][2]);
            }
            mx[mat][qi] = tmax;
          }
        }
      }
    }

    // merge the 4 rowgroup partials via shuffle
    #pragma unroll
    for (int off = 16; off <= 32; off <<= 1) {
      #pragma unroll
      for (int m = 0; m < 2; ++m)
        #pragma unroll
        for (int qi = 0; qi < 2; ++qi) {
          float m2 = __shfl_xor(mx[m][qi], off);
          float l2 = __shfl_xor(l[m][qi], off);
          float b0s = __shfl_xor(acc[m][qi][0], off);
          float b1s = __shfl_xor(acc[m][qi][1], off);
          float b2s = __shfl_xor(acc[m][qi][2], off);
          float mn = fmaxf(mx[m][qi], m2);
          float e1 = __expf(mx[m][qi] - mn), e2 = __expf(m2 - mn);
          l[m][qi] = l[m][qi] * e1 + l2 * e2;
          acc[m][qi][0] = acc[m][qi][0] * e1 + b0s * e2;
          acc[m][qi][1] = acc[m][qi][1] * e1 + b1s * e2;
          acc[m][qi][2] = acc[m][qi][2] * e1 + b2s * e2;
          mx[m][qi] = mn;
        }
    }
    if (rg == 0) {
      #pragma unroll
      for (int m = 0; m < 2; ++m)
        #pragma unroll
        for (int qi = 0; qi < 2; ++qi) {
          float* d = Mg[w][m][qi * 16 + r];
          d[0] = mx[m][qi]; d[1] = l[m][qi];
          d[2] = acc[m][qi][0]; d[3] = acc[m][qi][1]; d[4] = acc[m][qi][2];
        }
    }
    __syncthreads();

    // final cross-wave merge + output: one thread per q-row
    if (tid < 32) {
      const int q = tid;
      float res[2][3];
      #pragma unroll
      for (int m = 0; m < 2; ++m) {
        float M = -1e30f, L = 0.f, A0 = 0.f, A1 = 0.f, A2 = 0.f;
        #pragma unroll
        for (int ww = 0; ww < 8; ++ww) {
          const float* d = Mg[ww][m][q];
          float mn = fmaxf(M, d[0]);
          float e1 = __expf(M - mn), e2 = __expf(d[0] - mn);
          L = L * e1 + d[1] * e2;
          A0 = A0 * e1 + d[2] * e2;
          A1 = A1 * e1 + d[3] * e2;
          A2 = A2 * e1 + d[4] * e2;
          M = mn;
        }
        float iL = 1.0f / L;
        res[m][0] = A0 * iL; res[m][1] = A1 * iL; res[m][2] = A2 * iL;
      }
      const int maskv = seq_mask[b * SEQ + step];
      const int qg = q0 + q;
      float* ov = out + ((long)(b * STEPS + step) * HW + qg) * CV;
      float* po = pv_out + ((long)(b * HW + qg)) * CV;
      const float* vr = v + ((long)(b * SEQ + step) * HW + qg) * CV;
      #pragma unroll
      for (int c = 0; c < CV; ++c) {
        float rec = 0.9f * res[0][c] + 0.1f * res[1][c];  // COEF_MEMORY = 0.1
        ov[c] = rec;
        po[c] = maskv ? vr[c] : rec;
      }
    }

    // ---- software grid barrier (device-scope; all 256 blocks resident) ----
    if (step < STEPS - 1) {
      __syncthreads();                 // all threads done with this step's LDS
      if (tid == 0) {
        __threadfence();               // make pv_out/mv_out/out visible
        int* c = bar + step * 16;      // 64B-spaced counter per step
        __hip_atomic_fetch_add(c, 1, __ATOMIC_ACQ_REL, __HIP_MEMORY_SCOPE_AGENT);
        while (__hip_atomic_load(c, __ATOMIC_ACQUIRE, __HIP_MEMORY_SCOPE_AGENT)
               < NBLK)
          __builtin_amdgcn_s_sleep(2);
      }
      __syncthreads();                 // release all threads into next step
    }
  }
}

extern "C" void kernel_launch(void* const* d_in, const int* in_sizes, int n_in,
                              void* d_out, int out_size, void* d_ws, size_t ws_size,
                              hipStream_t stream) {
  const float* k   = (const float*)d_in[0];
  const float* v   = (const float*)d_in[1];
  const float* att = (const float*)d_in[2];
  const int* seq_mask = (const int*)d_in[3];
  float* out = (float*)d_out;
  char* ws = (char*)d_ws;

  // workspace layout (~130.4 MB of the 512 MiB ws):
  // kh_all | m_kh_all | pvA,pvB,mvA,mvB | barrier counters (1 KB)
  const size_t KH_ALL  = (size_t)BS * SEQ * HW * CK * 2;
  const size_t MKH_ALL = (size_t)BS * STEPS * HW * CK * 2;
  const size_t SV      = (size_t)BS * HW * CV * 4;

  u16*   kh_all   = (u16*)(ws);
  u16*   m_kh_all = (u16*)(ws + KH_ALL);
  float* pvA      = (float*)(ws + KH_ALL + MKH_ALL);
  float* pvB      = (float*)(ws + KH_ALL + MKH_ALL + SV);
  float* mvA      = (float*)(ws + KH_ALL + MKH_ALL + 2 * SV);
  float* mvB      = (float*)(ws + KH_ALL + MKH_ALL + 3 * SV);
  int*   bar      = (int*)(ws + KH_ALL + MKH_ALL + 4 * SV);

  // all conversions + m_k EMA scan + init + gt copy + barrier zeroing
  scan_state<<<2048, 256, 0, stream>>>(k, v, att, kh_all, m_kh_all, pvA, mvA,
                                       out, bar);

  // all 15 attention steps in ONE normal launch (software grid barrier)
  attn_span<<<dim3(BS, 32), 512, 0, stream>>>(kh_all, m_kh_all, v, seq_mask,
                                              att, mvA, mvB, pvA, pvB, out, bar);
}

// Round 10
// 467.639 us; speedup vs baseline: 2.3562x; 2.1703x over previous
//
#include <hip/hip_runtime.h>

// Problem: bs=8, seq=16, hw=32*32=1024, ck=256, cv=3, steps=seq-1=15
// R15 design: R10 structure (verified 720us, 15 separate launches) with the
// A-operand gather fixed at the LAYOUT level.
//  - R14 post-mortem: fused span gave body counters: MfmaUtil 6.3%, VALU
//    11.6%, HBM 1.1% -> ~80% stall. Cause: A-frag loads read 16B per lane
//    from rows 512B apart = 64 cache lines per instruction; 65K line-reqs
//    per CU per step ~= the measured 43us/step. Launch-tax theory dead
//    (fused was slower); spill theory dead (R13).
//  - Fix: kh_all/m_kh_all stored FRAGMENT-MAJOR: tile (pb=p>>4, kk) of 1KB,
//    granule g = lane = rg*16+r holds row pb*16+(g&15), cols kk*32+(g>>4)*8.
//    A-load: base + (pb*8+kk)*512 + lane*8 -> 1KB contiguous per wave inst
//    (16 lines, 4x fewer). MFMA math/fragments unchanged.
//  - scan_state: thread = (b, pb, kk, g) EMA chain -> granule writes are
//    1KB-contiguous per wave; transpose cost lives in the parallel kernel.
#define BS 8
#define SEQ 16
#define HW 1024
#define CK 256
#define CV 3
#define STEPS 15

#define SKP 264           // padded fp16 LDS row stride (256+8)
#define KSTR (HW * CK)    // u16 elements per (b,step) image = 262144

typedef unsigned short u16;
typedef _Float16 half8 __attribute__((ext_vector_type(8)));  // MFMA A/B frag
typedef float floatx4 __attribute__((ext_vector_type(4)));   // MFMA C/D frag

__device__ __forceinline__ u16 f2h(float f) {
  _Float16 h = (_Float16)f;
  return __builtin_bit_cast(unsigned short, h);
}
__device__ __forceinline__ float h2f(u16 u) {
  _Float16 h = __builtin_bit_cast(_Float16, u);
  return (float)h;
}

// ---- scan_state (once, fully parallel): kh_all = fp16(k[:, i]) for all i,
//      m_kh_all[i] = m_k EMA (fp16 state, fp32 math) -- both in FRAGMENT-MAJOR
//      tiled layout; pv0 = v[:,0], m_v0 = 0, gt = v[:,1:].
//      Thread = (b, pb, kk, g): one 8-elem granule's EMA chain over steps;
//      granule writes coalesce to 1KB per wave instruction. ----
__global__ __launch_bounds__(256) void scan_state(
    const float* __restrict__ k, const float* __restrict__ v,
    const float* __restrict__ att,
    u16* __restrict__ kh_all, u16* __restrict__ m_kh_all,
    float* __restrict__ pv0, float* __restrict__ mv0,
    float* __restrict__ out)
{
  long idx = (long)blockIdx.x * 256 + threadIdx.x;
  long stride = (long)gridDim.x * 256;
  const long NT = (long)BS * 64 * 8 * 64;      // 262,144 granule chains
  for (long t = idx; t < NT; t += stride) {
    long b = t >> 15;                          // / (64*8*64)
    long rr = t & 32767;
    long pb = rr >> 9;                         // p-block (64 per image)
    long kk = (rr >> 6) & 7;                   // k-column block
    long g  = rr & 63;                         // granule = lane = rg*16+r
    long p   = pb * 16 + (g & 15);             // row
    long col = kk * 32 + (g >> 4) * 8;         // first of 8 cols
    long toff = (pb * 8 + kk) * 512 + g * 8;   // u16 offset within image
    const float* kp = k + ((long)b * SEQ * HW + p) * CK + col;
    const float* ap = att + (long)b * SEQ * HW + p;
    u16 mh[8] = {0, 0, 0, 0, 0, 0, 0, 0};
    float4 nlo = *(const float4*)kp;
    float4 nhi = *(const float4*)(kp + 4);
    for (int i = 0; i < SEQ; ++i) {
      float4 lo = nlo, hi = nhi;
      if (i + 1 < SEQ) {
        nlo = *(const float4*)(kp + (long)(i + 1) * KSTR);
        nhi = *(const float4*)(kp + (long)(i + 1) * KSTR + 4);
      }
      float kf[8] = {lo.x, lo.y, lo.z, lo.w, hi.x, hi.y, hi.z, hi.w};
      u16 h8[8];
      #pragma unroll
      for (int j = 0; j < 8; ++j) h8[j] = f2h(kf[j]);
      *(int4*)(kh_all + (long)(b * SEQ + i) * KSTR + toff) = *(const int4*)h8;
      if (i < STEPS) {
        float a = ap[(long)i * HW];
        float gg = 1.0f / (1.0f + __expf(-a)), og = 1.0f - gg;
        #pragma unroll
        for (int j = 0; j < 8; ++j)
          mh[j] = f2h(fmaf(gg, kf[j], og * h2f(mh[j])));
        *(int4*)(m_kh_all + (long)(b * STEPS + i) * KSTR + toff) = *(const int4*)mh;
      }
    }
  }
  // pv0 = v[:,0], m_v0 = 0
  const long NV = (long)BS * HW * CV;
  for (long t = idx; t < NV; t += stride) {
    long b = t / (HW * CV), r = t - b * (HW * CV);
    pv0[t] = v[(long)b * SEQ * HW * CV + r];
    mv0[t] = 0.0f;
  }
  // gt = v[:,1:]
  const long NG = (long)BS * STEPS * HW * CV;
  for (long t = idx; t < NG; t += stride) {
    long b = t / (STEPS * HW * CV), r = t - b * (STEPS * HW * CV);
    long i = r / (HW * CV), rr = r - i * (HW * CV);
    out[NG + t] = v[((long)b * SEQ + i + 1) * (HW * CV) + rr];
  }
}

// --------- per-step fused dual-attention: barrier-free wave-autonomous ---------
// grid (BS, 32): block = (batch, 32 q-rows), 512 thr = 8 waves.
// Wave w owns p-range [w*128, (w+1)*128) as 4 chunks of 32.
// MFMA: A = p-rows (streamed from FRAGMENT-MAJOR layout: 1KB contiguous per
// wave instruction), B = q-tile (regs). D[p][q]: lane q=lane&15, p-rows =
// (lane>>4)*4+reg -> online softmax over p is in-register.
__global__ __launch_bounds__(512, 1) void attn_step(
    const u16* __restrict__ kh_all, const u16* __restrict__ m_kh_all,
    const float* __restrict__ v, const int* __restrict__ seq_mask,
    const float* __restrict__ att,
    const float* __restrict__ mv_in, float* __restrict__ mv_out,
    const float* __restrict__ pv_in, float* __restrict__ pv_out,
    float* __restrict__ out, int step)
{
  __shared__ u16 Kq[32 * SKP];          // q-tile fp16 (16.9 KB)
  __shared__ float Vp[HW * CV];         // prev_v staged (12 KB)
  __shared__ float Vm[HW * CV];         // m_v (updated) staged (12 KB)
  __shared__ float Mg[8][2][32][5];     // per-wave partial states (10.2 KB)

  const int b = blockIdx.x;
  const int q0 = blockIdx.y * 32;
  const int tid = threadIdx.x;
  const int w = tid >> 6, lane = tid & 63;
  const int r = lane & 15, rg = lane >> 4;

  const u16* Kn = kh_all + (long)(b * SEQ + step + 1) * KSTR;  // q side
  const u16* Kc = kh_all + (long)(b * SEQ + step) * KSTR;      // p side
  const u16* Mb = m_kh_all + (long)(b * STEPS + step) * KSTR;  // p side

  { // stage q-tile: 1024 16B-chunks, LINEAR reads from fragment-major layout
    #pragma unroll
    for (int j = 0; j < 2; ++j) {
      int c = tid + j * 512;
      int pbl = c >> 9, rem = c & 511;
      int kk2 = rem >> 6, g2 = rem & 63;
      int r2 = g2 & 15, rg2 = g2 >> 4;
      *(int4*)&Kq[(pbl * 16 + r2) * SKP + kk2 * 32 + rg2 * 8] =
          *(const int4*)(Kn + (long)(q0 >> 4) * 4096 + (long)c * 8);
    }
  }
  { // stage V values + fused m_v EMA: m_v_i = g*pv_i + (1-g)*m_v_{i-1}
    const float* ar = att + (long)(b * SEQ + step) * HW;
    #pragma unroll
    for (int j = 0; j < 2; ++j) {
      int row = tid + j * 512;
      float a = ar[row];
      float g = 1.0f / (1.0f + __expf(-a));
      float og = 1.0f - g;
      long base = (long)(b * HW + row) * CV;
      #pragma unroll
      for (int c = 0; c < CV; ++c) {
        float pv = pv_in[base + c];
        float mv = fmaf(g, pv, og * mv_in[base + c]);
        Vp[row * CV + c] = pv;
        Vm[row * CV + c] = mv;
        if (blockIdx.y == 0) mv_out[base + c] = mv;
      }
    }
  }
  __syncthreads();

  // B fragments (q-tile) held in registers: 2 q-subtiles x 8 k-steps
  half8 Bq[2][8];
  #pragma unroll
  for (int qi = 0; qi < 2; ++qi)
    #pragma unroll
    for (int kk = 0; kk < 8; ++kk)
      Bq[qi][kk] = *(const half8*)&Kq[(qi * 16 + r) * SKP + kk * 32 + rg * 8];

  // online state per (mat, qi): q-col = qi*16 + r, p-subset = this lane's rows
  float mx[2][2], l[2][2], acc[2][2][3];
  #pragma unroll
  for (int m = 0; m < 2; ++m)
    #pragma unroll
    for (int qi = 0; qi < 2; ++qi) {
      mx[m][qi] = -1e30f; l[m][qi] = 0.f;
      acc[m][qi][0] = acc[m][qi][1] = acc[m][qi][2] = 0.f;
    }

  #pragma unroll
  for (int pc = 0; pc < 4; ++pc) {
    const int p0 = w * 128 + pc * 32;
    #pragma unroll
    for (int mat = 0; mat < 2; ++mat) {
      const u16* Ab = mat ? Mb : Kc;
      const float* Vb = mat ? Vm : Vp;
      #pragma unroll
      for (int pi = 0; pi < 2; ++pi) {
        const int pr = p0 + pi * 16;
        const int pb = pr >> 4;                  // fragment-major tile row
        // V values for this lane's 4 p-rows, from LDS (broadcast within rg)
        float Vv[4][3];
        #pragma unroll
        for (int j = 0; j < 4; ++j) {
          const float* vp = Vb + (pr + rg * 4 + j) * CV;
          Vv[j][0] = vp[0]; Vv[j][1] = vp[1]; Vv[j][2] = vp[2];
        }
        // A fragments: 1KB-contiguous per wave instruction
        const u16* Abase = Ab + (long)pb * 4096 + lane * 8;
        half8 A[8];
        #pragma unroll
        for (int kk = 0; kk < 8; ++kk)
          A[kk] = *(const half8*)(Abase + kk * 512);
        floatx4 c0 = {0.f, 0.f, 0.f, 0.f}, c1 = {0.f, 0.f, 0.f, 0.f};
        #pragma unroll
        for (int kk = 0; kk < 8; ++kk) {
          c0 = __builtin_amdgcn_mfma_f32_16x16x32_f16(A[kk], Bq[0][kk], c0, 0, 0, 0);
          c1 = __builtin_amdgcn_mfma_f32_16x16x32_f16(A[kk], Bq[1][kk], c1, 0, 0, 0);
        }
        // absorb 4 p-values per qi into online state
        #pragma unroll
        for (int qi = 0; qi < 2; ++qi) {
          floatx4 cc = qi ? c1 : c0;
          float tmax = fmaxf(fmaxf(cc[0], cc[1]), fmaxf(cc[2], cc[3]));
          tmax = fmaxf(tmax, mx[mat][qi]);
          float sc = __expf(mx[mat][qi] - tmax);
          l[mat][qi] *= sc;
          acc[mat][qi][0] *= sc; acc[mat][qi][1] *= sc; acc[mat][qi][2] *= sc;
          #pragma unroll
          for (int j = 0; j < 4; ++j) {
            float e = __expf(cc[j] - tmax);
            l[mat][qi] += e;
            acc[mat][qi][0] = fmaf(e, Vv[j][0], acc[mat][qi][0]);
            acc[mat][qi][1] = fmaf(e, Vv[j][1], acc[mat][qi][1]);
            acc[mat][qi][2] = fmaf(e, Vv[j][2], acc[mat][qi][2]);
          }
          mx[mat][qi] = tmax;
        }
      }
    }
  }

  // merge the 4 rowgroup partials (lanes r, r+16, r+32, r+48) via shuffle
  #pragma unroll
  for (int off = 16; off <= 32; off <<= 1) {
    #pragma unroll
    for (int m = 0; m < 2; ++m)
      #pragma unroll
      for (int qi = 0; qi < 2; ++qi) {
        float m2 = __shfl_xor(mx[m][qi], off);
        float l2 = __shfl_xor(l[m][qi], off);
        float b0s = __shfl_xor(acc[m][qi][0], off);
        float b1s = __shfl_xor(acc[m][qi][1], off);
        float b2s = __shfl_xor(acc[m][qi][2], off);
        float mn = fmaxf(mx[m][qi], m2);
        float e1 = __expf(mx[m][qi] - mn), e2 = __expf(m2 - mn);
        l[m][qi] = l[m][qi] * e1 + l2 * e2;
        acc[m][qi][0] = acc[m][qi][0] * e1 + b0s * e2;
        acc[m][qi][1] = acc[m][qi][1] * e1 + b1s * e2;
        acc[m][qi][2] = acc[m][qi][2] * e1 + b2s * e2;
        mx[m][qi] = mn;
      }
  }
  if (rg == 0) {
    #pragma unroll
    for (int m = 0; m < 2; ++m)
      #pragma unroll
      for (int qi = 0; qi < 2; ++qi) {
        float* d = Mg[w][m][qi * 16 + r];
        d[0] = mx[m][qi]; d[1] = l[m][qi];
        d[2] = acc[m][qi][0]; d[3] = acc[m][qi][1]; d[4] = acc[m][qi][2];
      }
  }
  __syncthreads();

  // final cross-wave merge + output: one thread per q-row
  if (tid < 32) {
    const int q = tid;
    float res[2][3];
    #pragma unroll
    for (int m = 0; m < 2; ++m) {
      float M = -1e30f, L = 0.f, A0 = 0.f, A1 = 0.f, A2 = 0.f;
      #pragma unroll
      for (int ww = 0; ww < 8; ++ww) {
        const float* d = Mg[ww][m][q];
        float mn = fmaxf(M, d[0]);
        float e1 = __expf(M - mn), e2 = __expf(d[0] - mn);
        L = L * e1 + d[1] * e2;
        A0 = A0 * e1 + d[2] * e2;
        A1 = A1 * e1 + d[3] * e2;
        A2 = A2 * e1 + d[4] * e2;
        M = mn;
      }
      float iL = 1.0f / L;
      res[m][0] = A0 * iL; res[m][1] = A1 * iL; res[m][2] = A2 * iL;
    }
    const int maskv = seq_mask[b * SEQ + step];
    const int qg = q0 + q;
    float* ov = out + ((long)(b * STEPS + step) * HW + qg) * CV;
    float* po = pv_out + ((long)(b * HW + qg)) * CV;
    const float* vr = v + ((long)(b * SEQ + step) * HW + qg) * CV;
    #pragma unroll
    for (int c = 0; c < CV; ++c) {
      float rec = 0.9f * res[0][c] + 0.1f * res[1][c];  // COEF_MEMORY = 0.1
      ov[c] = rec;
      po[c] = maskv ? vr[c] : rec;
    }
  }
}

extern "C" void kernel_launch(void* const* d_in, const int* in_sizes, int n_in,
                              void* d_out, int out_size, void* d_ws, size_t ws_size,
                              hipStream_t stream) {
  const float* k   = (const float*)d_in[0];
  const float* v   = (const float*)d_in[1];
  const float* att = (const float*)d_in[2];
  const int* seq_mask = (const int*)d_in[3];
  float* out = (float*)d_out;
  char* ws = (char*)d_ws;

  // workspace layout (~130.4 MB of the 512 MiB ws):
  // kh_all 67,108,864 | m_kh_all 62,914,560 | pvA,pvB,mvA,mvB 4x98,304
  const size_t KH_ALL  = (size_t)BS * SEQ * HW * CK * 2;
  const size_t MKH_ALL = (size_t)BS * STEPS * HW * CK * 2;
  const size_t SV      = (size_t)BS * HW * CV * 4;

  u16*   kh_all   = (u16*)(ws);
  u16*   m_kh_all = (u16*)(ws + KH_ALL);
  float* pvA      = (float*)(ws + KH_ALL + MKH_ALL);
  float* pvB      = (float*)(ws + KH_ALL + MKH_ALL + SV);
  float* mvA      = (float*)(ws + KH_ALL + MKH_ALL + 2 * SV);
  float* mvB      = (float*)(ws + KH_ALL + MKH_ALL + 3 * SV);

  // one parallel kernel: all conversions + m_k scan + pv0/mv0 init + gt copy
  scan_state<<<1024, 256, 0, stream>>>(k, v, att, kh_all, m_kh_all, pvA, mvA, out);

  // serial chain: 15 attention steps only
  for (int i = 0; i < STEPS; ++i) {
    float* pin  = (i & 1) ? pvB : pvA;
    float* pout = (i & 1) ? pvA : pvB;
    float* mvi  = (i & 1) ? mvB : mvA;
    float* mvo  = (i & 1) ? mvA : mvB;
    attn_step<<<dim3(BS, 32), 512, 0, stream>>>(kh_all, m_kh_all, v, seq_mask,
                                                att, mvi, mvo, pin, pout, out, i);
  }
}